// Round 7
// baseline (956.258 us; speedup 1.0000x reference)
//
#include <hip/hip_runtime.h>
#include <hip/hip_bf16.h>
#include <math.h>

#define BB 4
#define LF 257      // NTOK+1
#define DMODEL 384
#define DIN 768
#define NST 16
#define DTR 24
#define XDB 56      // DTR + 2*N
#define POSROW 128
#define CL 16       // scan chunk length
#define NC 17       // ceil(LF/CL)

typedef __attribute__((ext_vector_type(8))) short short8;
typedef __attribute__((ext_vector_type(4))) float f32x4;

__device__ __forceinline__ float siluf(float v) { return v / (1.f + __expf(-v)); }
__device__ __forceinline__ float softplusf(float v) {
    return (v > 20.f) ? v : log1pf(__expf(v));
}
__device__ __forceinline__ short f2bf(float f) {
    unsigned u = __builtin_bit_cast(unsigned, f);
    unsigned r = (u + 0x7FFFu + ((u >> 16) & 1u)) >> 16;
    return (short)r;
}

// ---------------------------------------------------------------------------
// bf16-MFMA GEMM: C[m,n] = act( sum_k A[m,k]*W[n,k] + bias[n] ), f32 in/out.
// 64x64 tile, 256 thr = 4 waves in 2x2, each wave 2x2 mfma_f32_16x16x32_bf16.
// Staging: f32 global -> RNE bf16 -> LDS in fragment order (entry q*64+row,
// 16B each => conflict-free ds_read_b128 / 2-way ds_write). LDS dbuf + reg
// prefetch, one barrier per K-step(32).
// AMODE: 0 plain A, 1 patch gather, 2 flip-add(A+A2 row-reversed)
// SMODE: 0 plain(+bias), 1 softplus(+bias), 2 accumulate, 3 patchify store
// ---------------------------------------------------------------------------
template<int AMODE, int SMODE>
__device__ __forceinline__ void mgemm_core(
    const float* __restrict__ A, int lda,
    const float* __restrict__ W,
    const float* __restrict__ bias,
    float* __restrict__ Cout, int M, int N, int K,
    const float* __restrict__ gA, const float* __restrict__ A2,
    const float* __restrict__ pos,
    short* __restrict__ Ab, short* __restrict__ Wb)   // each 2*2048 shorts
{
    const int tid = threadIdx.x;
    const int m_s = tid >> 2;        // staging row 0..63
    const int q_s = tid & 3;         // staging k-quad 0..3
    const int bm = blockIdx.x * 64, bn = blockIdx.y * 64;
    const int lane = tid & 63;
    const int wv = tid >> 6;
    const int wm = (wv >> 1) * 32, wn = (wv & 1) * 32;
    const int qq = lane >> 4, lr = lane & 15;

    f32x4 acc[2][2];
    #pragma unroll
    for (int i = 0; i < 2; ++i)
        #pragma unroll
        for (int j = 0; j < 2; ++j)
            acc[i][j] = f32x4{0.f, 0.f, 0.f, 0.f};

    const int nsteps = (K + 31) >> 5;

    float4 pa[2], pw[2];
    const float4 z4 = make_float4(0.f, 0.f, 0.f, 0.f);

    auto loadA = [&](int k0) {
        int k = k0 + q_s * 8;
        int m = bm + m_s;
        if (AMODE == 0) {
            if (m < M && k < K) {
                pa[0] = *(const float4*)&A[(size_t)m * lda + k];
                pa[1] = *(const float4*)&A[(size_t)m * lda + k + 4];
            } else { pa[0] = z4; pa[1] = z4; }
        } else if (AMODE == 1) {
            int b = m >> 8, t = m & 255;
            int gh = t >> 3, gw = t & 7;
            int p1 = k >> 4, p2 = k & 15;
            const float* src = &gA[(size_t)b * 65536 + gh * 2048 + p1 * 128 + gw * 16 + p2];
            pa[0] = *(const float4*)src;
            pa[1] = *(const float4*)(src + 4);
        } else {  // flip-add
            if (m < M && k < K) {
                int b = m / LF, l = m - b * LF;
                const float* s1 = &A[(size_t)m * lda + k];
                const float* s2 = &A2[(size_t)(b * LF + (LF - 1 - l)) * lda + k];
                float4 x0 = *(const float4*)s1, x1 = *(const float4*)(s1 + 4);
                float4 y0 = *(const float4*)s2, y1 = *(const float4*)(s2 + 4);
                pa[0] = make_float4(x0.x + y0.x, x0.y + y0.y, x0.z + y0.z, x0.w + y0.w);
                pa[1] = make_float4(x1.x + y1.x, x1.y + y1.y, x1.z + y1.z, x1.w + y1.w);
            } else { pa[0] = z4; pa[1] = z4; }
        }
    };
    auto loadW = [&](int k0) {
        int k = k0 + q_s * 8;
        int n = bn + m_s;
        if (n < N && k < K) {
            pw[0] = *(const float4*)&W[(size_t)n * K + k];
            pw[1] = *(const float4*)&W[(size_t)n * K + k + 4];
        } else { pw[0] = z4; pw[1] = z4; }
    };
    auto cvt8 = [&](float4 a, float4 b) -> short8 {
        short8 r;
        r[0] = f2bf(a.x); r[1] = f2bf(a.y); r[2] = f2bf(a.z); r[3] = f2bf(a.w);
        r[4] = f2bf(b.x); r[5] = f2bf(b.y); r[6] = f2bf(b.z); r[7] = f2bf(b.w);
        return r;
    };

    loadA(0);
    loadW(0);

    for (int s = 0; s < nsteps; ++s) {
        const int buf = (s & 1) * 2048;
        *(short8*)&Ab[buf + (q_s * 64 + m_s) * 8] = cvt8(pa[0], pa[1]);
        *(short8*)&Wb[buf + (q_s * 64 + m_s) * 8] = cvt8(pw[0], pw[1]);
        __syncthreads();
        if (s + 1 < nsteps) { loadA((s + 1) * 32); loadW((s + 1) * 32); }
        short8 af0 = *(const short8*)&Ab[buf + (qq * 64 + wm + lr) * 8];
        short8 af1 = *(const short8*)&Ab[buf + (qq * 64 + wm + 16 + lr) * 8];
        short8 wf0 = *(const short8*)&Wb[buf + (qq * 64 + wn + lr) * 8];
        short8 wf1 = *(const short8*)&Wb[buf + (qq * 64 + wn + 16 + lr) * 8];
        acc[0][0] = __builtin_amdgcn_mfma_f32_16x16x32_bf16(af0, wf0, acc[0][0], 0, 0, 0);
        acc[0][1] = __builtin_amdgcn_mfma_f32_16x16x32_bf16(af0, wf1, acc[0][1], 0, 0, 0);
        acc[1][0] = __builtin_amdgcn_mfma_f32_16x16x32_bf16(af1, wf0, acc[1][0], 0, 0, 0);
        acc[1][1] = __builtin_amdgcn_mfma_f32_16x16x32_bf16(af1, wf1, acc[1][1], 0, 0, 0);
    }

    #pragma unroll
    for (int mi = 0; mi < 2; ++mi) {
        #pragma unroll
        for (int ni = 0; ni < 2; ++ni) {
            int col = bn + wn + ni * 16 + lr;
            if (col >= N) continue;
            #pragma unroll
            for (int r = 0; r < 4; ++r) {
                int row = bm + wm + mi * 16 + qq * 4 + r;
                if (row >= M) continue;
                float v = acc[mi][ni][r];
                if (SMODE == 0) {
                    if (bias) v += bias[col];
                    Cout[(size_t)row * N + col] = v;
                } else if (SMODE == 1) {
                    v += bias[col];
                    Cout[(size_t)row * N + col] = softplusf(v);
                } else if (SMODE == 2) {
                    Cout[(size_t)row * N + col] += v;
                } else {  // patchify store with cls gap + pos
                    int b = row >> 8, t = row & 255;
                    int l = (t < POSROW) ? t : t + 1;
                    v += bias[col] + pos[(size_t)l * DMODEL + col];
                    Cout[(size_t)(b * LF + l) * DMODEL + col] = v;
                }
            }
        }
    }
}

template<int AMODE, int SMODE>
__global__ __launch_bounds__(256) void mgemm_k(
    const float* __restrict__ A, int lda,
    const float* __restrict__ W, const float* __restrict__ bias,
    float* __restrict__ Cout, int M, int N, int K,
    const float* __restrict__ gA, const float* __restrict__ A2,
    const float* __restrict__ pos)
{
    __shared__ __align__(16) short Ab[2 * 2048];
    __shared__ __align__(16) short Wb[2 * 2048];
    mgemm_core<AMODE, SMODE>(A, lda, W, bias, Cout, M, N, K, gA, A2, pos, Ab, Wb);
}

// dual-dispatch (fwd/bwd branch) via blockIdx.z
template<int SMODE>
__global__ __launch_bounds__(256) void mgemm_pair_k(
    const float* __restrict__ A0, const float* __restrict__ W0,
    const float* __restrict__ b0, float* __restrict__ C0,
    const float* __restrict__ A1, const float* __restrict__ W1,
    const float* __restrict__ b1, float* __restrict__ C1,
    int lda, int M, int N, int K)
{
    __shared__ __align__(16) short Ab[2 * 2048];
    __shared__ __align__(16) short Wb[2 * 2048];
    if (blockIdx.z == 0)
        mgemm_core<0, SMODE>(A0, lda, W0, b0, C0, M, N, K, nullptr, nullptr, nullptr, Ab, Wb);
    else
        mgemm_core<0, SMODE>(A1, lda, W1, b1, C1, M, N, K, nullptr, nullptr, nullptr, Ab, Wb);
}

// cls row: residual[b, 128, :] = cls + pos[128]
__global__ void cls_k(const float* __restrict__ cls, const float* __restrict__ pos,
                      float* __restrict__ residual) {
    int b = blockIdx.x, t = threadIdx.x;
    residual[(size_t)(b * LF + POSROW) * DMODEL + t] =
        cls[t] + pos[(size_t)POSROW * DMODEL + t];
}

// row-wise layernorm over 384
__global__ __launch_bounds__(128) void ln_k(const float* __restrict__ X,
                                            const float* __restrict__ w,
                                            const float* __restrict__ b,
                                            float* __restrict__ Y) {
    int r = blockIdx.x;
    const float* x = X + (size_t)r * DMODEL;
    int t = threadIdx.x;
    float v0 = x[t], v1 = x[t + 128], v2 = x[t + 256];
    float s = v0 + v1 + v2;
    float sq = v0 * v0 + v1 * v1 + v2 * v2;
    #pragma unroll
    for (int o = 32; o > 0; o >>= 1) {
        s += __shfl_down(s, o);
        sq += __shfl_down(sq, o);
    }
    __shared__ float ls[2], lq[2];
    if ((t & 63) == 0) { ls[t >> 6] = s; lq[t >> 6] = sq; }
    __syncthreads();
    float S = ls[0] + ls[1], Q = lq[0] + lq[1];
    float mean = S * (1.f / 384.f);
    float var = Q * (1.f / 384.f) - mean * mean;
    float rs = rsqrtf(var + 1e-5f);
    float* y = Y + (size_t)r * DMODEL;
    y[t]       = (v0 - mean) * rs * w[t]       + b[t];
    y[t + 128] = (v1 - mean) * rs * w[t + 128] + b[t + 128];
    y[t + 256] = (v2 - mean) * rs * w[t + 256] + b[t + 256];
}

// fused fwd+bwd causal depthwise conv (K=4) + SiLU
__global__ __launch_bounds__(256) void conv_k(
    const float* __restrict__ xz,
    const float* __restrict__ cw, const float* __restrict__ cb,
    const float* __restrict__ cwb, const float* __restrict__ cbb,
    float* __restrict__ xcf, float* __restrict__ xcb) {
    int g = blockIdx.x * 256 + threadIdx.x;
    if (g >= BB * LF * DIN) return;
    int d = g % DIN;
    int rm = g / DIN;
    int b = rm / LF, l = rm - b * LF;
    const float* xb = xz + (size_t)b * LF * (2 * DIN);
    float wf[4], wb[4];
    #pragma unroll
    for (int k = 0; k < 4; ++k) {
        wf[k] = cw[d * 4 + k];
        wb[k] = cwb[d * 4 + k];
    }
    float af = cb[d], ab = cbb[d];
    #pragma unroll
    for (int k = 0; k < 4; ++k) {
        int li = l - 3 + k;
        if (li >= 0) {
            af += xb[(size_t)li * (2 * DIN) + d] * wf[k];
            ab += xb[(size_t)(LF - 1 - li) * (2 * DIN) + d] * wb[k];
        }
    }
    xcf[(size_t)rm * DIN + d] = siluf(af);
    xcb[(size_t)rm * DIN + d] = siluf(ab);
}

// ---------------------------------------------------------------------------
// Chunked associative scan (round-6 structure, unchanged math).
// ---------------------------------------------------------------------------
__global__ __launch_bounds__(256) void scanA_k(
    const float* __restrict__ xcf, const float* __restrict__ dtf,
    const float* __restrict__ xdbf,
    const float* __restrict__ xcb, const float* __restrict__ dtb,
    const float* __restrict__ xdbb,
    const float* __restrict__ alf, const float* __restrict__ alb,
    float* __restrict__ hpart, float* __restrict__ sumd) {
    const int t = threadIdx.x;
    const int y = blockIdx.y;            // b*2+br
    const int b = y >> 1, br = y & 1;
    const int c = blockIdx.z;
    const int d = blockIdx.x * 256 + t;
    const float* xc  = br ? xcb  : xcf;
    const float* dt  = br ? dtb  : dtf;
    const float* xdb = br ? xdbb : xdbf;
    const float* Al  = br ? alb  : alf;

    float An[NST];
    #pragma unroll
    for (int n = 0; n < NST; ++n) An[n] = -__expf(Al[(size_t)d * NST + n]);

    __shared__ float sB[CL][NST];
    {
        int s0 = t >> 4, j0 = t & 15;
        int l0 = c * CL + s0;
        sB[s0][j0] = (l0 < LF) ? xdb[(size_t)(b * LF + l0) * XDB + DTR + j0] : 0.f;
    }
    __syncthreads();

    float h[NST] = {};
    float sdt = 0.f;
    #pragma unroll
    for (int s = 0; s < CL; ++s) {
        int l = c * CL + s;
        if (l < LF) {
            int row = b * LF + l;
            float dtv = dt[(size_t)row * DIN + d];
            float xcv = xc[(size_t)row * DIN + d];
            sdt += dtv;
            float dtx = dtv * xcv;
            #pragma unroll
            for (int n = 0; n < NST; ++n)
                h[n] = __expf(dtv * An[n]) * h[n] + dtx * sB[s][n];
        }
    }
    size_t base = (size_t)(c * 8 + y) * NST;
    #pragma unroll
    for (int n = 0; n < NST; ++n) hpart[(base + n) * DIN + d] = h[n];
    sumd[(size_t)(c * 8 + y) * DIN + d] = sdt;
}

__global__ __launch_bounds__(256) void scanC_k(
    const float* __restrict__ xcf, const float* __restrict__ dtf,
    const float* __restrict__ xdbf,
    const float* __restrict__ xcb, const float* __restrict__ dtb,
    const float* __restrict__ xdbb,
    const float* __restrict__ xz,
    const float* __restrict__ alf, const float* __restrict__ dpf,
    const float* __restrict__ alb, const float* __restrict__ dpb,
    const float* __restrict__ hpart, const float* __restrict__ sumd,
    float* __restrict__ yf, float* __restrict__ yb) {
    const int t = threadIdx.x;
    const int y = blockIdx.y;
    const int b = y >> 1, br = y & 1;
    const int c = blockIdx.z;
    const int d = blockIdx.x * 256 + t;
    const float* xc  = br ? xcb  : xcf;
    const float* dt  = br ? dtb  : dtf;
    const float* xdb = br ? xdbb : xdbf;
    const float* Al  = br ? alb  : alf;
    const float* Dpp = br ? dpb  : dpf;
    float* yo        = br ? yb   : yf;

    float An[NST];
    #pragma unroll
    for (int n = 0; n < NST; ++n) An[n] = -__expf(Al[(size_t)d * NST + n]);
    float Dv = Dpp[d];

    __shared__ float sB[CL][NST];
    __shared__ float sC[CL][NST];
    {
        int s0 = t >> 4, j0 = t & 15;
        int l0 = c * CL + s0;
        size_t rb = (size_t)(b * LF + l0) * XDB + DTR;
        sB[s0][j0] = (l0 < LF) ? xdb[rb + j0] : 0.f;
        sC[s0][j0] = (l0 < LF) ? xdb[rb + NST + j0] : 0.f;
    }
    __syncthreads();

    float h[NST] = {};
    for (int j = 0; j < c; ++j) {
        float sd = sumd[(size_t)(j * 8 + y) * DIN + d];
        size_t base = (size_t)(j * 8 + y) * NST;
        #pragma unroll
        for (int n = 0; n < NST; ++n)
            h[n] = __expf(An[n] * sd) * h[n] + hpart[(base + n) * DIN + d];
    }

    #pragma unroll
    for (int s = 0; s < CL; ++s) {
        int l = c * CL + s;
        if (l < LF) {
            int row = b * LF + l;
            float dtv = dt[(size_t)row * DIN + d];
            float xcv = xc[(size_t)row * DIN + d];
            int zl = br ? (LF - 1 - l) : l;
            float zv = xz[(size_t)(b * LF + zl) * (2 * DIN) + DIN + d];
            float dtx = dtv * xcv;
            float acc = 0.f;
            #pragma unroll
            for (int n = 0; n < NST; ++n) {
                h[n] = __expf(dtv * An[n]) * h[n] + dtx * sB[s][n];
                acc += h[n] * sC[s][n];
            }
            yo[(size_t)row * DIN + d] = (acc + xcv * Dv) * siluf(zv);
        }
    }
}

// final LN(row POS) + command MLP + add -> f32 out
__global__ __launch_bounds__(384) void final_k(
    const float* __restrict__ residual,
    const float* __restrict__ lnw, const float* __restrict__ lnb,
    const float* __restrict__ sv, const float* __restrict__ act,
    const float* __restrict__ cw1, const float* __restrict__ cb1,
    const float* __restrict__ cw2, const float* __restrict__ cb2,
    float* __restrict__ out) {
    int b = blockIdx.x, t = threadIdx.x;
    const float* x = residual + (size_t)(b * LF + POSROW) * DMODEL;
    float v = x[t];
    float s = v, sq = v * v;
    #pragma unroll
    for (int o = 32; o > 0; o >>= 1) {
        s += __shfl_down(s, o);
        sq += __shfl_down(sq, o);
    }
    __shared__ float ls[6], lq[6], hid[DMODEL], cmdin[20];
    if ((t & 63) == 0) { ls[t >> 6] = s; lq[t >> 6] = sq; }
    if (t < 20) cmdin[t] = (t < 16) ? sv[b * 16 + t] : act[b * 4 + t - 16];
    __syncthreads();
    float S = 0.f, Q = 0.f;
    #pragma unroll
    for (int w = 0; w < 6; ++w) { S += ls[w]; Q += lq[w]; }
    float mean = S * (1.f / 384.f);
    float var = Q * (1.f / 384.f) - mean * mean;
    float rs = rsqrtf(var + 1e-5f);
    float vis = (v - mean) * rs * lnw[t] + lnb[t];
    float a1 = cb1[t];
    #pragma unroll
    for (int k = 0; k < 20; ++k) a1 += cmdin[k] * cw1[t * 20 + k];
    hid[t] = fmaxf(a1, 0.f);
    __syncthreads();
    float a2 = cb2[t];
    for (int k = 0; k < DMODEL; ++k) a2 += hid[k] * cw2[t * DMODEL + k];
    out[b * DMODEL + t] = vis + a2;
}

extern "C" void kernel_launch(void* const* d_in, const int* in_sizes, int n_in,
                              void* d_out, int out_size, void* d_ws, size_t ws_size,
                              hipStream_t stream) {
    const float* depth_seq = (const float*)d_in[0];
    const float* state_vec = (const float*)d_in[1];
    const float* action    = (const float*)d_in[2];
    const float* patch_w   = (const float*)d_in[3];
    const float* patch_b   = (const float*)d_in[4];
    const float* cls_token = (const float*)d_in[5];
    const float* pos_embed = (const float*)d_in[6];
    const float* ln_w      = (const float*)d_in[7];
    const float* ln_b      = (const float*)d_in[8];
    const float* in_proj_w = (const float*)d_in[9];
    const float* conv_w    = (const float*)d_in[10];
    const float* conv_b    = (const float*)d_in[11];
    const float* conv_wb   = (const float*)d_in[12];
    const float* conv_bb   = (const float*)d_in[13];
    const float* xproj_w   = (const float*)d_in[14];
    const float* xproj_wb  = (const float*)d_in[15];
    const float* dtproj_w  = (const float*)d_in[16];
    const float* dtproj_b  = (const float*)d_in[17];
    const float* dtproj_wb = (const float*)d_in[18];
    const float* dtproj_bb = (const float*)d_in[19];
    const float* A_log     = (const float*)d_in[20];
    const float* A_logb    = (const float*)d_in[21];
    const float* Dp        = (const float*)d_in[22];
    const float* Dpb       = (const float*)d_in[23];
    const float* out_w     = (const float*)d_in[24];
    const float* lnf_w     = (const float*)d_in[25];
    const float* lnf_b     = (const float*)d_in[26];
    const float* cw1       = (const float*)d_in[27];
    const float* cb1       = (const float*)d_in[28];
    const float* cw2       = (const float*)d_in[29];
    const float* cb2       = (const float*)d_in[30];

    const int M = BB * LF;  // 1028
    float* ws = (float*)d_ws;
    size_t o = 0;
    float* residual = ws + o; o += (size_t)M * DMODEL;
    float* h_ln     = ws + o; o += (size_t)M * DMODEL;
    float* xz       = ws + o; o += (size_t)M * 2 * DIN;
    float* xcf      = ws + o; o += (size_t)M * DIN;
    float* xcb      = ws + o; o += (size_t)M * DIN;
    float* xdbf     = ws + o; o += (size_t)M * XDB;
    float* xdbb     = ws + o; o += (size_t)M * XDB;
    float* dtf      = ws + o; o += (size_t)M * DIN;
    float* dtb      = ws + o; o += (size_t)M * DIN;
    float* yfb      = ws + o; o += (size_t)M * DIN;
    float* ybb      = ws + o; o += (size_t)M * DIN;
    float* hpart    = ws + o; o += (size_t)NC * 8 * NST * DIN;
    float* sumd     = ws + o; o += (size_t)NC * 8 * DIN;
    (void)ws_size; (void)in_sizes; (void)n_in; (void)out_size;

    // patchify -> residual (bias + pos, cls gap), MFMA
    mgemm_k<1, 3><<<dim3(16, 6), 256, 0, stream>>>(
        nullptr, 0, patch_w, patch_b, residual, 1024, DMODEL, 256,
        depth_seq, nullptr, pos_embed);
    cls_k<<<BB, DMODEL, 0, stream>>>(cls_token, pos_embed, residual);

    for (int i = 0; i < 4; ++i) {
        ln_k<<<M, 128, 0, stream>>>(residual, ln_w + (size_t)i * DMODEL,
                                    ln_b + (size_t)i * DMODEL, h_ln);
        // in_proj: (1028 x 384) @ (384 x 1536)^T
        mgemm_k<0, 0><<<dim3(17, 24), 256, 0, stream>>>(
            h_ln, DMODEL, in_proj_w + (size_t)i * 2 * DIN * DMODEL, nullptr,
            xz, M, 2 * DIN, DMODEL, nullptr, nullptr, nullptr);
        conv_k<<<(BB * LF * DIN) / 256, 256, 0, stream>>>(
            xz, conv_w + (size_t)i * DIN * 4, conv_b + (size_t)i * DIN,
            conv_wb + (size_t)i * DIN * 4, conv_bb + (size_t)i * DIN, xcf, xcb);
        // x_proj fwd+bwd: (1028 x 768) @ (768 x 56)^T
        mgemm_pair_k<0><<<dim3(17, 1, 2), 256, 0, stream>>>(
            xcf, xproj_w  + (size_t)i * XDB * DIN, nullptr, xdbf,
            xcb, xproj_wb + (size_t)i * XDB * DIN, nullptr, xdbb,
            DIN, M, XDB, DIN);
        // dt fwd+bwd: (1028 x 24) @ (24 x 768)^T + softplus
        mgemm_pair_k<1><<<dim3(17, 12, 2), 256, 0, stream>>>(
            xdbf, dtproj_w  + (size_t)i * DIN * DTR, dtproj_b  + (size_t)i * DIN, dtf,
            xdbb, dtproj_wb + (size_t)i * DIN * DTR, dtproj_bb + (size_t)i * DIN, dtb,
            XDB, M, DIN, DTR);
        // chunked scan
        scanA_k<<<dim3(3, 8, NC), 256, 0, stream>>>(
            xcf, dtf, xdbf, xcb, dtb, xdbb,
            A_log + (size_t)i * DIN * NST, A_logb + (size_t)i * DIN * NST,
            hpart, sumd);
        scanC_k<<<dim3(3, 8, NC), 256, 0, stream>>>(
            xcf, dtf, xdbf, xcb, dtb, xdbb, xz,
            A_log + (size_t)i * DIN * NST, Dp + (size_t)i * DIN,
            A_logb + (size_t)i * DIN * NST, Dpb + (size_t)i * DIN,
            hpart, sumd, yfb, ybb);
        // out_proj with fused flip-add, residual += (MFMA)
        mgemm_k<2, 2><<<dim3(17, 6), 256, 0, stream>>>(
            yfb, DIN, out_w + (size_t)i * DMODEL * DIN, nullptr,
            residual, M, DMODEL, DIN, nullptr, ybb, nullptr);
    }

    final_k<<<BB, DMODEL, 0, stream>>>(
        residual, lnf_w, lnf_b, state_vec, action, cw1, cb1, cw2, cb2,
        (float*)d_out);
}

// Round 8
// 658.008 us; speedup vs baseline: 1.4533x; 1.4533x over previous
//
#include <hip/hip_runtime.h>
#include <hip/hip_bf16.h>
#include <math.h>

#define BB 4
#define LF 257      // NTOK+1
#define DMODEL 384
#define DIN 768
#define NST 16
#define DTR 24
#define XDB 56      // DTR + 2*N
#define POSROW 128
#define CL 16       // scan chunk length
#define NC 17       // ceil(LF/CL)

typedef __attribute__((ext_vector_type(8))) short short8;
typedef __attribute__((ext_vector_type(4))) float f32x4;

__device__ __forceinline__ float siluf(float v) { return v / (1.f + __expf(-v)); }
__device__ __forceinline__ float softplusf(float v) {
    return (v > 20.f) ? v : log1pf(__expf(v));
}
__device__ __forceinline__ short f2bf(float f) {
    unsigned u = __builtin_bit_cast(unsigned, f);
    unsigned r = (u + 0x7FFFu + ((u >> 16) & 1u)) >> 16;
    return (short)r;
}

// ---------------------------------------------------------------------------
// bf16-MFMA GEMM core over K range [kb,ke): C[m,n] (+)= sum A[m,k]*W[n,k].
// 64x64 tile, 4 waves (2x2), each wave 2x2 mfma_f32_16x16x32_bf16.
// AMODE: 0 plain A, 1 patch gather, 2 flip-add, 3 LN-fused
//        (AMODE3 reuses gA=stats(float2: mean,rstd), A2=lnw, pos=lnb)
// SMODE: 0 plain(+bias), 1 softplus(+bias), 3 patchify store,
//        4 atomicAdd (split-K partials; also residual accumulate)
// ---------------------------------------------------------------------------
template<int AMODE, int SMODE>
__device__ __forceinline__ void mgemm_core(
    const float* __restrict__ A, int lda,
    const float* __restrict__ W,
    const float* __restrict__ bias,
    float* __restrict__ Cout, int M, int N, int K, int kb, int ke, int bn,
    const float* __restrict__ gA, const float* __restrict__ A2,
    const float* __restrict__ pos,
    short* __restrict__ Ab, short* __restrict__ Wb)   // each 2*2048 shorts
{
    const int tid = threadIdx.x;
    const int m_s = tid >> 2;        // staging row 0..63
    const int q_s = tid & 3;         // staging k-quad 0..3
    const int bm = blockIdx.x * 64;
    const int lane = tid & 63;
    const int wv = tid >> 6;
    const int wm = (wv >> 1) * 32, wn = (wv & 1) * 32;
    const int qq = lane >> 4, lr = lane & 15;

    f32x4 acc[2][2];
    #pragma unroll
    for (int i = 0; i < 2; ++i)
        #pragma unroll
        for (int j = 0; j < 2; ++j)
            acc[i][j] = f32x4{0.f, 0.f, 0.f, 0.f};

    float4 pa[2], pw[2];
    const float4 z4 = make_float4(0.f, 0.f, 0.f, 0.f);

    auto loadA = [&](int k0) {
        int k = k0 + q_s * 8;
        int m = bm + m_s;
        if (AMODE == 0) {
            if (m < M && k < K) {
                pa[0] = *(const float4*)&A[(size_t)m * lda + k];
                pa[1] = *(const float4*)&A[(size_t)m * lda + k + 4];
            } else { pa[0] = z4; pa[1] = z4; }
        } else if (AMODE == 1) {
            int b = m >> 8, t = m & 255;
            int gh = t >> 3, gw = t & 7;
            int p1 = k >> 4, p2 = k & 15;
            const float* src = &gA[(size_t)b * 65536 + gh * 2048 + p1 * 128 + gw * 16 + p2];
            pa[0] = *(const float4*)src;
            pa[1] = *(const float4*)(src + 4);
        } else if (AMODE == 2) {  // flip-add
            if (m < M && k < K) {
                int b = m / LF, l = m - b * LF;
                const float* s1 = &A[(size_t)m * lda + k];
                const float* s2 = &A2[(size_t)(b * LF + (LF - 1 - l)) * lda + k];
                float4 x0 = *(const float4*)s1, x1 = *(const float4*)(s1 + 4);
                float4 y0 = *(const float4*)s2, y1 = *(const float4*)(s2 + 4);
                pa[0] = make_float4(x0.x + y0.x, x0.y + y0.y, x0.z + y0.z, x0.w + y0.w);
                pa[1] = make_float4(x1.x + y1.x, x1.y + y1.y, x1.z + y1.z, x1.w + y1.w);
            } else { pa[0] = z4; pa[1] = z4; }
        } else {  // AMODE 3: LayerNorm fused during staging
            if (m < M && k < K) {
                float2 st = ((const float2*)gA)[m];
                float4 r0 = *(const float4*)&A[(size_t)m * lda + k];
                float4 r1 = *(const float4*)&A[(size_t)m * lda + k + 4];
                float4 w0 = *(const float4*)&A2[k],  w1 = *(const float4*)&A2[k + 4];
                float4 b0 = *(const float4*)&pos[k], b1 = *(const float4*)&pos[k + 4];
                pa[0] = make_float4((r0.x - st.x) * st.y * w0.x + b0.x,
                                    (r0.y - st.x) * st.y * w0.y + b0.y,
                                    (r0.z - st.x) * st.y * w0.z + b0.z,
                                    (r0.w - st.x) * st.y * w0.w + b0.w);
                pa[1] = make_float4((r1.x - st.x) * st.y * w1.x + b1.x,
                                    (r1.y - st.x) * st.y * w1.y + b1.y,
                                    (r1.z - st.x) * st.y * w1.z + b1.z,
                                    (r1.w - st.x) * st.y * w1.w + b1.w);
            } else { pa[0] = z4; pa[1] = z4; }
        }
    };
    auto loadW = [&](int k0) {
        int k = k0 + q_s * 8;
        int n = bn + m_s;
        if (n < N && k < K) {
            pw[0] = *(const float4*)&W[(size_t)n * K + k];
            pw[1] = *(const float4*)&W[(size_t)n * K + k + 4];
        } else { pw[0] = z4; pw[1] = z4; }
    };
    auto cvt8 = [&](float4 a, float4 b) -> short8 {
        short8 r;
        r[0] = f2bf(a.x); r[1] = f2bf(a.y); r[2] = f2bf(a.z); r[3] = f2bf(a.w);
        r[4] = f2bf(b.x); r[5] = f2bf(b.y); r[6] = f2bf(b.z); r[7] = f2bf(b.w);
        return r;
    };

    loadA(kb);
    loadW(kb);

    int s = 0;
    for (int k0 = kb; k0 < ke; k0 += 32, ++s) {
        const int buf = (s & 1) * 2048;
        *(short8*)&Ab[buf + (q_s * 64 + m_s) * 8] = cvt8(pa[0], pa[1]);
        *(short8*)&Wb[buf + (q_s * 64 + m_s) * 8] = cvt8(pw[0], pw[1]);
        __syncthreads();
        if (k0 + 32 < ke) { loadA(k0 + 32); loadW(k0 + 32); }
        short8 af0 = *(const short8*)&Ab[buf + (qq * 64 + wm + lr) * 8];
        short8 af1 = *(const short8*)&Ab[buf + (qq * 64 + wm + 16 + lr) * 8];
        short8 wf0 = *(const short8*)&Wb[buf + (qq * 64 + wn + lr) * 8];
        short8 wf1 = *(const short8*)&Wb[buf + (qq * 64 + wn + 16 + lr) * 8];
        acc[0][0] = __builtin_amdgcn_mfma_f32_16x16x32_bf16(af0, wf0, acc[0][0], 0, 0, 0);
        acc[0][1] = __builtin_amdgcn_mfma_f32_16x16x32_bf16(af0, wf1, acc[0][1], 0, 0, 0);
        acc[1][0] = __builtin_amdgcn_mfma_f32_16x16x32_bf16(af1, wf0, acc[1][0], 0, 0, 0);
        acc[1][1] = __builtin_amdgcn_mfma_f32_16x16x32_bf16(af1, wf1, acc[1][1], 0, 0, 0);
    }

    #pragma unroll
    for (int mi = 0; mi < 2; ++mi) {
        #pragma unroll
        for (int ni = 0; ni < 2; ++ni) {
            int col = bn + wn + ni * 16 + lr;
            if (col >= N) continue;
            #pragma unroll
            for (int r = 0; r < 4; ++r) {
                int row = bm + wm + mi * 16 + qq * 4 + r;
                if (row >= M) continue;
                float v = acc[mi][ni][r];
                if (SMODE == 0) {
                    if (bias) v += bias[col];
                    Cout[(size_t)row * N + col] = v;
                } else if (SMODE == 1) {
                    v += bias[col];
                    Cout[(size_t)row * N + col] = softplusf(v);
                } else if (SMODE == 3) {  // patchify store with cls gap + pos
                    int b = row >> 8, t = row & 255;
                    int l = (t < POSROW) ? t : t + 1;
                    v += bias[col] + pos[(size_t)l * DMODEL + col];
                    Cout[(size_t)(b * LF + l) * DMODEL + col] = v;
                } else {  // SMODE 4: split-K partial / accumulate
                    atomicAdd(&Cout[(size_t)row * N + col], v);
                }
            }
        }
    }
}

// grid: (Mtiles, Ntiles*KS); blockIdx.y -> (ntile, ks)
template<int AMODE, int SMODE>
__global__ __launch_bounds__(256) void mgemm_k(
    const float* __restrict__ A, int lda,
    const float* __restrict__ W, const float* __restrict__ bias,
    float* __restrict__ Cout, int M, int N, int K, int KS,
    const float* __restrict__ gA, const float* __restrict__ A2,
    const float* __restrict__ pos)
{
    __shared__ __align__(16) short Ab[2 * 2048];
    __shared__ __align__(16) short Wb[2 * 2048];
    int ntile = blockIdx.y / KS, ks = blockIdx.y % KS;
    int chunk = K / KS;
    mgemm_core<AMODE, SMODE>(A, lda, W, bias, Cout, M, N, K,
                             ks * chunk, ks * chunk + chunk, ntile * 64,
                             gA, A2, pos, Ab, Wb);
}

// dual-dispatch (fwd/bwd) with split-K: grid (Mtiles, Ntiles*KS, 2)
template<int SMODE>
__global__ __launch_bounds__(256) void mgemm_pair_k(
    const float* __restrict__ A0, const float* __restrict__ W0,
    const float* __restrict__ b0, float* __restrict__ C0,
    const float* __restrict__ A1, const float* __restrict__ W1,
    const float* __restrict__ b1, float* __restrict__ C1,
    int lda, int M, int N, int K, int KS)
{
    __shared__ __align__(16) short Ab[2 * 2048];
    __shared__ __align__(16) short Wb[2 * 2048];
    int ntile = blockIdx.y / KS, ks = blockIdx.y % KS;
    int chunk = K / KS;
    int kb = ks * chunk, ke = kb + chunk, bn = ntile * 64;
    if (blockIdx.z == 0)
        mgemm_core<0, SMODE>(A0, lda, W0, b0, C0, M, N, K, kb, ke, bn,
                             nullptr, nullptr, nullptr, Ab, Wb);
    else
        mgemm_core<0, SMODE>(A1, lda, W1, b1, C1, M, N, K, kb, ke, bn,
                             nullptr, nullptr, nullptr, Ab, Wb);
}

// cls row: residual[b, 128, :] = cls + pos[128]
__global__ void cls_k(const float* __restrict__ cls, const float* __restrict__ pos,
                      float* __restrict__ residual) {
    int b = blockIdx.x, t = threadIdx.x;
    residual[(size_t)(b * LF + POSROW) * DMODEL + t] =
        cls[t] + pos[(size_t)POSROW * DMODEL + t];
}

// row-wise layernorm STATS over 384 -> (mean, rstd) per row
__global__ __launch_bounds__(128) void lnstat_k(const float* __restrict__ X,
                                                float2* __restrict__ st) {
    int r = blockIdx.x;
    const float* x = X + (size_t)r * DMODEL;
    int t = threadIdx.x;
    float v0 = x[t], v1 = x[t + 128], v2 = x[t + 256];
    float s = v0 + v1 + v2;
    float sq = v0 * v0 + v1 * v1 + v2 * v2;
    #pragma unroll
    for (int o = 32; o > 0; o >>= 1) {
        s += __shfl_down(s, o);
        sq += __shfl_down(sq, o);
    }
    __shared__ float ls[2], lq[2];
    if ((t & 63) == 0) { ls[t >> 6] = s; lq[t >> 6] = sq; }
    __syncthreads();
    if (t == 0) {
        float S = ls[0] + ls[1], Q = lq[0] + lq[1];
        float mean = S * (1.f / 384.f);
        float var = Q * (1.f / 384.f) - mean * mean;
        st[r] = make_float2(mean, rsqrtf(var + 1e-5f));
    }
}

// fused fwd+bwd causal depthwise conv (K=4) + SiLU
__global__ __launch_bounds__(256) void conv_k(
    const float* __restrict__ xz,
    const float* __restrict__ cw, const float* __restrict__ cb,
    const float* __restrict__ cwb, const float* __restrict__ cbb,
    float* __restrict__ xcf, float* __restrict__ xcb) {
    int g = blockIdx.x * 256 + threadIdx.x;
    if (g >= BB * LF * DIN) return;
    int d = g % DIN;
    int rm = g / DIN;
    int b = rm / LF, l = rm - b * LF;
    const float* xb = xz + (size_t)b * LF * (2 * DIN);
    float wf[4], wb[4];
    #pragma unroll
    for (int k = 0; k < 4; ++k) {
        wf[k] = cw[d * 4 + k];
        wb[k] = cwb[d * 4 + k];
    }
    float af = cb[d], ab = cbb[d];
    #pragma unroll
    for (int k = 0; k < 4; ++k) {
        int li = l - 3 + k;
        if (li >= 0) {
            af += xb[(size_t)li * (2 * DIN) + d] * wf[k];
            ab += xb[(size_t)(LF - 1 - li) * (2 * DIN) + d] * wb[k];
        }
    }
    xcf[(size_t)rm * DIN + d] = siluf(af);
    xcb[(size_t)rm * DIN + d] = siluf(ab);
}

// ---------------------------------------------------------------------------
// Chunked associative scan (unchanged math).
// ---------------------------------------------------------------------------
__global__ __launch_bounds__(256) void scanA_k(
    const float* __restrict__ xcf, const float* __restrict__ dtf,
    const float* __restrict__ xdbf,
    const float* __restrict__ xcb, const float* __restrict__ dtb,
    const float* __restrict__ xdbb,
    const float* __restrict__ alf, const float* __restrict__ alb,
    float* __restrict__ hpart, float* __restrict__ sumd) {
    const int t = threadIdx.x;
    const int y = blockIdx.y;            // b*2+br
    const int b = y >> 1, br = y & 1;
    const int c = blockIdx.z;
    const int d = blockIdx.x * 256 + t;
    const float* xc  = br ? xcb  : xcf;
    const float* dt  = br ? dtb  : dtf;
    const float* xdb = br ? xdbb : xdbf;
    const float* Al  = br ? alb  : alf;

    float An[NST];
    #pragma unroll
    for (int n = 0; n < NST; ++n) An[n] = -__expf(Al[(size_t)d * NST + n]);

    __shared__ float sB[CL][NST];
    {
        int s0 = t >> 4, j0 = t & 15;
        int l0 = c * CL + s0;
        sB[s0][j0] = (l0 < LF) ? xdb[(size_t)(b * LF + l0) * XDB + DTR + j0] : 0.f;
    }
    __syncthreads();

    float h[NST] = {};
    float sdt = 0.f;
    #pragma unroll
    for (int s = 0; s < CL; ++s) {
        int l = c * CL + s;
        if (l < LF) {
            int row = b * LF + l;
            float dtv = dt[(size_t)row * DIN + d];
            float xcv = xc[(size_t)row * DIN + d];
            sdt += dtv;
            float dtx = dtv * xcv;
            #pragma unroll
            for (int n = 0; n < NST; ++n)
                h[n] = __expf(dtv * An[n]) * h[n] + dtx * sB[s][n];
        }
    }
    size_t base = (size_t)(c * 8 + y) * NST;
    #pragma unroll
    for (int n = 0; n < NST; ++n) hpart[(base + n) * DIN + d] = h[n];
    sumd[(size_t)(c * 8 + y) * DIN + d] = sdt;
}

__global__ __launch_bounds__(256) void scanC_k(
    const float* __restrict__ xcf, const float* __restrict__ dtf,
    const float* __restrict__ xdbf,
    const float* __restrict__ xcb, const float* __restrict__ dtb,
    const float* __restrict__ xdbb,
    const float* __restrict__ xz,
    const float* __restrict__ alf, const float* __restrict__ dpf,
    const float* __restrict__ alb, const float* __restrict__ dpb,
    const float* __restrict__ hpart, const float* __restrict__ sumd,
    float* __restrict__ yf, float* __restrict__ yb) {
    const int t = threadIdx.x;
    const int y = blockIdx.y;
    const int b = y >> 1, br = y & 1;
    const int c = blockIdx.z;
    const int d = blockIdx.x * 256 + t;
    const float* xc  = br ? xcb  : xcf;
    const float* dt  = br ? dtb  : dtf;
    const float* xdb = br ? xdbb : xdbf;
    const float* Al  = br ? alb  : alf;
    const float* Dpp = br ? dpb  : dpf;
    float* yo        = br ? yb   : yf;

    float An[NST];
    #pragma unroll
    for (int n = 0; n < NST; ++n) An[n] = -__expf(Al[(size_t)d * NST + n]);
    float Dv = Dpp[d];

    __shared__ float sB[CL][NST];
    __shared__ float sC[CL][NST];
    {
        int s0 = t >> 4, j0 = t & 15;
        int l0 = c * CL + s0;
        size_t rb = (size_t)(b * LF + l0) * XDB + DTR;
        sB[s0][j0] = (l0 < LF) ? xdb[rb + j0] : 0.f;
        sC[s0][j0] = (l0 < LF) ? xdb[rb + NST + j0] : 0.f;
    }
    __syncthreads();

    float h[NST] = {};
    for (int j = 0; j < c; ++j) {
        float sd = sumd[(size_t)(j * 8 + y) * DIN + d];
        size_t base = (size_t)(j * 8 + y) * NST;
        #pragma unroll
        for (int n = 0; n < NST; ++n)
            h[n] = __expf(An[n] * sd) * h[n] + hpart[(base + n) * DIN + d];
    }

    #pragma unroll
    for (int s = 0; s < CL; ++s) {
        int l = c * CL + s;
        if (l < LF) {
            int row = b * LF + l;
            float dtv = dt[(size_t)row * DIN + d];
            float xcv = xc[(size_t)row * DIN + d];
            int zl = br ? (LF - 1 - l) : l;
            float zv = xz[(size_t)(b * LF + zl) * (2 * DIN) + DIN + d];
            float dtx = dtv * xcv;
            float acc = 0.f;
            #pragma unroll
            for (int n = 0; n < NST; ++n) {
                h[n] = __expf(dtv * An[n]) * h[n] + dtx * sB[s][n];
                acc += h[n] * sC[s][n];
            }
            yo[(size_t)row * DIN + d] = (acc + xcv * Dv) * siluf(zv);
        }
    }
}

// final LN(row POS) + command MLP + add -> f32 out
__global__ __launch_bounds__(384) void final_k(
    const float* __restrict__ residual,
    const float* __restrict__ lnw, const float* __restrict__ lnb,
    const float* __restrict__ sv, const float* __restrict__ act,
    const float* __restrict__ cw1, const float* __restrict__ cb1,
    const float* __restrict__ cw2, const float* __restrict__ cb2,
    float* __restrict__ out) {
    int b = blockIdx.x, t = threadIdx.x;
    const float* x = residual + (size_t)(b * LF + POSROW) * DMODEL;
    float v = x[t];
    float s = v, sq = v * v;
    #pragma unroll
    for (int o = 32; o > 0; o >>= 1) {
        s += __shfl_down(s, o);
        sq += __shfl_down(sq, o);
    }
    __shared__ float ls[6], lq[6], hid[DMODEL], cmdin[20];
    if ((t & 63) == 0) { ls[t >> 6] = s; lq[t >> 6] = sq; }
    if (t < 20) cmdin[t] = (t < 16) ? sv[b * 16 + t] : act[b * 4 + t - 16];
    __syncthreads();
    float S = 0.f, Q = 0.f;
    #pragma unroll
    for (int w = 0; w < 6; ++w) { S += ls[w]; Q += lq[w]; }
    float mean = S * (1.f / 384.f);
    float var = Q * (1.f / 384.f) - mean * mean;
    float rs = rsqrtf(var + 1e-5f);
    float vis = (v - mean) * rs * lnw[t] + lnb[t];
    float a1 = cb1[t];
    #pragma unroll
    for (int k = 0; k < 20; ++k) a1 += cmdin[k] * cw1[t * 20 + k];
    hid[t] = fmaxf(a1, 0.f);
    __syncthreads();
    float a2 = cb2[t];
    for (int k = 0; k < DMODEL; ++k) a2 += hid[k] * cw2[t * DMODEL + k];
    out[b * DMODEL + t] = vis + a2;
}

extern "C" void kernel_launch(void* const* d_in, const int* in_sizes, int n_in,
                              void* d_out, int out_size, void* d_ws, size_t ws_size,
                              hipStream_t stream) {
    const float* depth_seq = (const float*)d_in[0];
    const float* state_vec = (const float*)d_in[1];
    const float* action    = (const float*)d_in[2];
    const float* patch_w   = (const float*)d_in[3];
    const float* patch_b   = (const float*)d_in[4];
    const float* cls_token = (const float*)d_in[5];
    const float* pos_embed = (const float*)d_in[6];
    const float* ln_w      = (const float*)d_in[7];
    const float* ln_b      = (const float*)d_in[8];
    const float* in_proj_w = (const float*)d_in[9];
    const float* conv_w    = (const float*)d_in[10];
    const float* conv_b    = (const float*)d_in[11];
    const float* conv_wb   = (const float*)d_in[12];
    const float* conv_bb   = (const float*)d_in[13];
    const float* xproj_w   = (const float*)d_in[14];
    const float* xproj_wb  = (const float*)d_in[15];
    const float* dtproj_w  = (const float*)d_in[16];
    const float* dtproj_b  = (const float*)d_in[17];
    const float* dtproj_wb = (const float*)d_in[18];
    const float* dtproj_bb = (const float*)d_in[19];
    const float* A_log     = (const float*)d_in[20];
    const float* A_logb    = (const float*)d_in[21];
    const float* Dp        = (const float*)d_in[22];
    const float* Dpb       = (const float*)d_in[23];
    const float* out_w     = (const float*)d_in[24];
    const float* lnf_w     = (const float*)d_in[25];
    const float* lnf_b     = (const float*)d_in[26];
    const float* cw1       = (const float*)d_in[27];
    const float* cb1       = (const float*)d_in[28];
    const float* cw2       = (const float*)d_in[29];
    const float* cb2       = (const float*)d_in[30];

    const int M = BB * LF;  // 1028
    float* ws = (float*)d_ws;
    size_t o = 0;
    float* residual = ws + o; o += (size_t)M * DMODEL;
    float* xz       = ws + o; o += (size_t)M * 2 * DIN;
    float* xcf      = ws + o; o += (size_t)M * DIN;
    float* xcb      = ws + o; o += (size_t)M * DIN;
    float* xdbf     = ws + o; o += (size_t)M * XDB;
    float* xdbb     = ws + o; o += (size_t)M * XDB;
    float* dtf      = ws + o; o += (size_t)M * DIN;
    float* dtb      = ws + o; o += (size_t)M * DIN;
    float* yfb      = ws + o; o += (size_t)M * DIN;
    float* ybb      = ws + o; o += (size_t)M * DIN;
    float* hpart    = ws + o; o += (size_t)NC * 8 * NST * DIN;
    float* sumd     = ws + o; o += (size_t)NC * 8 * DIN;
    float2* stats   = (float2*)(ws + o); o += (size_t)M * 2;
    (void)ws_size; (void)in_sizes; (void)n_in; (void)out_size;

    // patchify -> residual (bias + pos, cls gap), MFMA
    mgemm_k<1, 3><<<dim3(16, 6), 256, 0, stream>>>(
        nullptr, 0, patch_w, patch_b, residual, 1024, DMODEL, 256, 1,
        depth_seq, nullptr, pos_embed);
    cls_k<<<BB, DMODEL, 0, stream>>>(cls_token, pos_embed, residual);

    for (int i = 0; i < 4; ++i) {
        lnstat_k<<<M, 128, 0, stream>>>(residual, stats);
        // in_proj with fused LN: (1028 x 384) @ (384 x 1536)^T
        mgemm_k<3, 0><<<dim3(17, 24), 256, 0, stream>>>(
            residual, DMODEL, in_proj_w + (size_t)i * 2 * DIN * DMODEL, nullptr,
            xz, M, 2 * DIN, DMODEL, 1,
            (const float*)stats, ln_w + (size_t)i * DMODEL, ln_b + (size_t)i * DMODEL);
        conv_k<<<(BB * LF * DIN) / 256, 256, 0, stream>>>(
            xz, conv_w + (size_t)i * DIN * 4, conv_b + (size_t)i * DIN,
            conv_wb + (size_t)i * DIN * 4, conv_bb + (size_t)i * DIN, xcf, xcb);
        // x_proj fwd+bwd, split-K 8 with atomic partials
        hipMemsetAsync(xdbf, 0, (size_t)M * XDB * 4, stream);
        hipMemsetAsync(xdbb, 0, (size_t)M * XDB * 4, stream);
        mgemm_pair_k<4><<<dim3(17, 8, 2), 256, 0, stream>>>(
            xcf, xproj_w  + (size_t)i * XDB * DIN, nullptr, xdbf,
            xcb, xproj_wb + (size_t)i * XDB * DIN, nullptr, xdbb,
            DIN, M, XDB, DIN, 8);
        // dt fwd+bwd: (1028 x 24) @ (24 x 768)^T + softplus (K=24, one step)
        mgemm_pair_k<1><<<dim3(17, 12, 2), 256, 0, stream>>>(
            xdbf, dtproj_w  + (size_t)i * DIN * DTR, dtproj_b  + (size_t)i * DIN, dtf,
            xdbb, dtproj_wb + (size_t)i * DIN * DTR, dtproj_bb + (size_t)i * DIN, dtb,
            XDB, M, DIN, DTR, 1);
        // chunked scan
        scanA_k<<<dim3(3, 8, NC), 256, 0, stream>>>(
            xcf, dtf, xdbf, xcb, dtb, xdbb,
            A_log + (size_t)i * DIN * NST, A_logb + (size_t)i * DIN * NST,
            hpart, sumd);
        scanC_k<<<dim3(3, 8, NC), 256, 0, stream>>>(
            xcf, dtf, xdbf, xcb, dtb, xdbb, xz,
            A_log + (size_t)i * DIN * NST, Dp + (size_t)i * DIN,
            A_logb + (size_t)i * DIN * NST, Dpb + (size_t)i * DIN,
            hpart, sumd, yfb, ybb);
        // out_proj flip-add, split-K 4, atomicAdd accumulate into residual
        mgemm_k<2, 4><<<dim3(17, 6 * 4), 256, 0, stream>>>(
            yfb, DIN, out_w + (size_t)i * DMODEL * DIN, nullptr,
            residual, M, DMODEL, DIN, 4, nullptr, ybb, nullptr);
    }

    final_k<<<BB, DMODEL, 0, stream>>>(
        residual, lnf_w, lnf_b, state_vec, action, cw1, cb1, cw2, cb2,
        (float*)d_out);
}

// Round 9
// 653.213 us; speedup vs baseline: 1.4639x; 1.0073x over previous
//
#include <hip/hip_runtime.h>
#include <hip/hip_bf16.h>
#include <math.h>

#define BB 4
#define LF 257      // NTOK+1
#define DMODEL 384
#define DIN 768
#define NST 16
#define DTR 24
#define XDB 56      // DTR + 2*N
#define POSROW 128
#define CL 16       // scan chunk length
#define NC 17       // ceil(LF/CL)

typedef __attribute__((ext_vector_type(8))) short short8;
typedef __attribute__((ext_vector_type(4))) float f32x4;

__device__ __forceinline__ float siluf(float v) { return v / (1.f + __expf(-v)); }
__device__ __forceinline__ float softplusf(float v) {
    return (v > 20.f) ? v : log1pf(__expf(v));
}
__device__ __forceinline__ short f2bf(float f) {
    unsigned u = __builtin_bit_cast(unsigned, f);
    unsigned r = (u + 0x7FFFu + ((u >> 16) & 1u)) >> 16;
    return (short)r;
}

// ---------------------------------------------------------------------------
// bf16-MFMA GEMM core over K range [kb,ke): C[m,n] (+)= sum A[m,k]*W[n,k].
// 64x64 tile, 4 waves (2x2), each wave 2x2 mfma_f32_16x16x32_bf16.
// AMODE: 1 patch gather, 2 flip-add, 3 LN-fused (gA=stats, A2=lnw, pos=lnb)
// SMODE: 0 plain(+bias), 3 patchify store, 4 atomicAdd (split-K / accumulate)
// ---------------------------------------------------------------------------
template<int AMODE, int SMODE>
__device__ __forceinline__ void mgemm_core(
    const float* __restrict__ A, int lda,
    const float* __restrict__ W,
    const float* __restrict__ bias,
    float* __restrict__ Cout, int M, int N, int K, int kb, int ke, int bn,
    const float* __restrict__ gA, const float* __restrict__ A2,
    const float* __restrict__ pos,
    short* __restrict__ Ab, short* __restrict__ Wb)
{
    const int tid = threadIdx.x;
    const int m_s = tid >> 2;
    const int q_s = tid & 3;
    const int bm = blockIdx.x * 64;
    const int lane = tid & 63;
    const int wv = tid >> 6;
    const int wm = (wv >> 1) * 32, wn = (wv & 1) * 32;
    const int qq = lane >> 4, lr = lane & 15;

    f32x4 acc[2][2];
    #pragma unroll
    for (int i = 0; i < 2; ++i)
        #pragma unroll
        for (int j = 0; j < 2; ++j)
            acc[i][j] = f32x4{0.f, 0.f, 0.f, 0.f};

    float4 pa[2], pw[2];
    const float4 z4 = make_float4(0.f, 0.f, 0.f, 0.f);

    auto loadA = [&](int k0) {
        int k = k0 + q_s * 8;
        int m = bm + m_s;
        if (AMODE == 1) {
            int b = m >> 8, t = m & 255;
            int gh = t >> 3, gw = t & 7;
            int p1 = k >> 4, p2 = k & 15;
            const float* src = &gA[(size_t)b * 65536 + gh * 2048 + p1 * 128 + gw * 16 + p2];
            pa[0] = *(const float4*)src;
            pa[1] = *(const float4*)(src + 4);
        } else if (AMODE == 2) {  // flip-add
            if (m < M && k < K) {
                int b = m / LF, l = m - b * LF;
                const float* s1 = &A[(size_t)m * lda + k];
                const float* s2 = &A2[(size_t)(b * LF + (LF - 1 - l)) * lda + k];
                float4 x0 = *(const float4*)s1, x1 = *(const float4*)(s1 + 4);
                float4 y0 = *(const float4*)s2, y1 = *(const float4*)(s2 + 4);
                pa[0] = make_float4(x0.x + y0.x, x0.y + y0.y, x0.z + y0.z, x0.w + y0.w);
                pa[1] = make_float4(x1.x + y1.x, x1.y + y1.y, x1.z + y1.z, x1.w + y1.w);
            } else { pa[0] = z4; pa[1] = z4; }
        } else {  // AMODE 3: LayerNorm fused during staging
            if (m < M && k < K) {
                float2 st = ((const float2*)gA)[m];
                float4 r0 = *(const float4*)&A[(size_t)m * lda + k];
                float4 r1 = *(const float4*)&A[(size_t)m * lda + k + 4];
                float4 w0 = *(const float4*)&A2[k],  w1 = *(const float4*)&A2[k + 4];
                float4 b0 = *(const float4*)&pos[k], b1 = *(const float4*)&pos[k + 4];
                pa[0] = make_float4((r0.x - st.x) * st.y * w0.x + b0.x,
                                    (r0.y - st.x) * st.y * w0.y + b0.y,
                                    (r0.z - st.x) * st.y * w0.z + b0.z,
                                    (r0.w - st.x) * st.y * w0.w + b0.w);
                pa[1] = make_float4((r1.x - st.x) * st.y * w1.x + b1.x,
                                    (r1.y - st.x) * st.y * w1.y + b1.y,
                                    (r1.z - st.x) * st.y * w1.z + b1.z,
                                    (r1.w - st.x) * st.y * w1.w + b1.w);
            } else { pa[0] = z4; pa[1] = z4; }
        }
    };
    auto loadW = [&](int k0) {
        int k = k0 + q_s * 8;
        int n = bn + m_s;
        if (n < N && k < K) {
            pw[0] = *(const float4*)&W[(size_t)n * K + k];
            pw[1] = *(const float4*)&W[(size_t)n * K + k + 4];
        } else { pw[0] = z4; pw[1] = z4; }
    };
    auto cvt8 = [&](float4 a, float4 b) -> short8 {
        short8 r;
        r[0] = f2bf(a.x); r[1] = f2bf(a.y); r[2] = f2bf(a.z); r[3] = f2bf(a.w);
        r[4] = f2bf(b.x); r[5] = f2bf(b.y); r[6] = f2bf(b.z); r[7] = f2bf(b.w);
        return r;
    };

    loadA(kb);
    loadW(kb);

    int s = 0;
    for (int k0 = kb; k0 < ke; k0 += 32, ++s) {
        const int buf = (s & 1) * 2048;
        *(short8*)&Ab[buf + (q_s * 64 + m_s) * 8] = cvt8(pa[0], pa[1]);
        *(short8*)&Wb[buf + (q_s * 64 + m_s) * 8] = cvt8(pw[0], pw[1]);
        __syncthreads();
        if (k0 + 32 < ke) { loadA(k0 + 32); loadW(k0 + 32); }
        short8 af0 = *(const short8*)&Ab[buf + (qq * 64 + wm + lr) * 8];
        short8 af1 = *(const short8*)&Ab[buf + (qq * 64 + wm + 16 + lr) * 8];
        short8 wf0 = *(const short8*)&Wb[buf + (qq * 64 + wn + lr) * 8];
        short8 wf1 = *(const short8*)&Wb[buf + (qq * 64 + wn + 16 + lr) * 8];
        acc[0][0] = __builtin_amdgcn_mfma_f32_16x16x32_bf16(af0, wf0, acc[0][0], 0, 0, 0);
        acc[0][1] = __builtin_amdgcn_mfma_f32_16x16x32_bf16(af0, wf1, acc[0][1], 0, 0, 0);
        acc[1][0] = __builtin_amdgcn_mfma_f32_16x16x32_bf16(af1, wf0, acc[1][0], 0, 0, 0);
        acc[1][1] = __builtin_amdgcn_mfma_f32_16x16x32_bf16(af1, wf1, acc[1][1], 0, 0, 0);
    }

    #pragma unroll
    for (int mi = 0; mi < 2; ++mi) {
        #pragma unroll
        for (int ni = 0; ni < 2; ++ni) {
            int col = bn + wn + ni * 16 + lr;
            if (col >= N) continue;
            #pragma unroll
            for (int r = 0; r < 4; ++r) {
                int row = bm + wm + mi * 16 + qq * 4 + r;
                if (row >= M) continue;
                float v = acc[mi][ni][r];
                if (SMODE == 0) {
                    if (bias) v += bias[col];
                    Cout[(size_t)row * N + col] = v;
                } else if (SMODE == 3) {
                    int b = row >> 8, t = row & 255;
                    int l = (t < POSROW) ? t : t + 1;
                    v += bias[col] + pos[(size_t)l * DMODEL + col];
                    Cout[(size_t)(b * LF + l) * DMODEL + col] = v;
                } else {  // SMODE 4
                    atomicAdd(&Cout[(size_t)row * N + col], v);
                }
            }
        }
    }
}

template<int AMODE, int SMODE>
__global__ __launch_bounds__(256) void mgemm_k(
    const float* __restrict__ A, int lda,
    const float* __restrict__ W, const float* __restrict__ bias,
    float* __restrict__ Cout, int M, int N, int K, int KS,
    const float* __restrict__ gA, const float* __restrict__ A2,
    const float* __restrict__ pos)
{
    __shared__ __align__(16) short Ab[2 * 2048];
    __shared__ __align__(16) short Wb[2 * 2048];
    int ntile = blockIdx.y / KS, ks = blockIdx.y % KS;
    int chunk = K / KS;
    mgemm_core<AMODE, SMODE>(A, lda, W, bias, Cout, M, N, K,
                             ks * chunk, ks * chunk + chunk, ntile * 64,
                             gA, A2, pos, Ab, Wb);
}

// ---------------------------------------------------------------------------
// Fused conv(K=4)+SiLU -> xproj MFMA. grid (17 m-tiles, 8 k-chunks, 2 branch).
// Each block stages a UNIQUE (m-tile, k-chunk) of xc (N-tiles==1): computes
// conv from xz during A-staging, stores xc to global as side product, runs
// 3 MFMA K-steps, atomicAdd partials into xdb (pre-zeroed).
// ---------------------------------------------------------------------------
__global__ __launch_bounds__(256) void xp_k(
    const float* __restrict__ xz,
    const float* __restrict__ cwf, const float* __restrict__ cbf,
    const float* __restrict__ cwb, const float* __restrict__ cbb,
    const float* __restrict__ Wf, const float* __restrict__ Wb,
    float* __restrict__ xcf, float* __restrict__ xcb,
    float* __restrict__ xdbf, float* __restrict__ xdbb)
{
    __shared__ __align__(16) short Ash[2 * 2048];
    __shared__ __align__(16) short Wsh[2 * 2048];
    const int br = blockIdx.z;
    const float* cw = br ? cwb : cwf;
    const float* cbv = br ? cbb : cbf;
    const float* W  = br ? Wb  : Wf;
    float* xco      = br ? xcb : xcf;
    float* xdo      = br ? xdbb : xdbf;

    const int tid = threadIdx.x;
    const int m_s = tid >> 2, q_s = tid & 3;
    const int bm = blockIdx.x * 64;
    const int kb = blockIdx.y * 96;
    const int lane = tid & 63, wv = tid >> 6;
    const int wm = (wv >> 1) * 32, wn = (wv & 1) * 32;
    const int qq = lane >> 4, lr = lane & 15;
    const int m = bm + m_s;
    const bool mok = (m < BB * LF);
    int b = 0, l = 0;
    if (mok) { b = m / LF; l = m - b * LF; }

    f32x4 acc[2][2];
    #pragma unroll
    for (int i = 0; i < 2; ++i)
        #pragma unroll
        for (int j = 0; j < 2; ++j)
            acc[i][j] = f32x4{0.f, 0.f, 0.f, 0.f};

    float a8[8];
    float4 pw0, pw1;
    const float4 z4 = make_float4(0.f, 0.f, 0.f, 0.f);

    auto loadA = [&](int k0) {
        int d0 = k0 + q_s * 8;
        if (mok) {
            float4 c0 = *(const float4*)&cbv[d0];
            float4 c1 = *(const float4*)&cbv[d0 + 4];
            a8[0] = c0.x; a8[1] = c0.y; a8[2] = c0.z; a8[3] = c0.w;
            a8[4] = c1.x; a8[5] = c1.y; a8[6] = c1.z; a8[7] = c1.w;
            float wreg[8][4];
            #pragma unroll
            for (int j = 0; j < 8; ++j)
                *(float4*)wreg[j] = *(const float4*)&cw[(d0 + j) * 4];
            #pragma unroll
            for (int kk = 0; kk < 4; ++kk) {
                int li = l - 3 + kk;
                if (li >= 0) {
                    int srow = br ? (b * LF + (LF - 1 - li)) : (b * LF + li);
                    const float* xp = &xz[(size_t)srow * 2 * DIN + d0];
                    float4 x0 = *(const float4*)xp, x1 = *(const float4*)(xp + 4);
                    a8[0] += x0.x * wreg[0][kk]; a8[1] += x0.y * wreg[1][kk];
                    a8[2] += x0.z * wreg[2][kk]; a8[3] += x0.w * wreg[3][kk];
                    a8[4] += x1.x * wreg[4][kk]; a8[5] += x1.y * wreg[5][kk];
                    a8[6] += x1.z * wreg[6][kk]; a8[7] += x1.w * wreg[7][kk];
                }
            }
            #pragma unroll
            for (int j = 0; j < 8; ++j) a8[j] = siluf(a8[j]);
        } else {
            #pragma unroll
            for (int j = 0; j < 8; ++j) a8[j] = 0.f;
        }
    };
    auto loadW = [&](int k0) {
        int k = k0 + q_s * 8;
        if (m_s < XDB) {
            pw0 = *(const float4*)&W[(size_t)m_s * DIN + k];
            pw1 = *(const float4*)&W[(size_t)m_s * DIN + k + 4];
        } else { pw0 = z4; pw1 = z4; }
    };
    auto cvt8f = [&]() -> short8 {
        short8 r;
        #pragma unroll
        for (int j = 0; j < 8; ++j) r[j] = f2bf(a8[j]);
        return r;
    };
    auto cvt8w = [&]() -> short8 {
        short8 r;
        r[0] = f2bf(pw0.x); r[1] = f2bf(pw0.y); r[2] = f2bf(pw0.z); r[3] = f2bf(pw0.w);
        r[4] = f2bf(pw1.x); r[5] = f2bf(pw1.y); r[6] = f2bf(pw1.z); r[7] = f2bf(pw1.w);
        return r;
    };

    loadA(kb);
    loadW(kb);

    #pragma unroll
    for (int s = 0; s < 3; ++s) {
        const int k0 = kb + s * 32;
        const int buf = (s & 1) * 2048;
        *(short8*)&Ash[buf + (q_s * 64 + m_s) * 8] = cvt8f();
        *(short8*)&Wsh[buf + (q_s * 64 + m_s) * 8] = cvt8w();
        if (mok) {  // side-product: materialize xc for the scan kernels
            int d0 = k0 + q_s * 8;
            *(float4*)&xco[(size_t)m * DIN + d0] =
                make_float4(a8[0], a8[1], a8[2], a8[3]);
            *(float4*)&xco[(size_t)m * DIN + d0 + 4] =
                make_float4(a8[4], a8[5], a8[6], a8[7]);
        }
        __syncthreads();
        if (s + 1 < 3) { loadA(k0 + 32); loadW(k0 + 32); }
        short8 af0 = *(const short8*)&Ash[buf + (qq * 64 + wm + lr) * 8];
        short8 af1 = *(const short8*)&Ash[buf + (qq * 64 + wm + 16 + lr) * 8];
        short8 wf0 = *(const short8*)&Wsh[buf + (qq * 64 + wn + lr) * 8];
        short8 wf1 = *(const short8*)&Wsh[buf + (qq * 64 + wn + 16 + lr) * 8];
        acc[0][0] = __builtin_amdgcn_mfma_f32_16x16x32_bf16(af0, wf0, acc[0][0], 0, 0, 0);
        acc[0][1] = __builtin_amdgcn_mfma_f32_16x16x32_bf16(af0, wf1, acc[0][1], 0, 0, 0);
        acc[1][0] = __builtin_amdgcn_mfma_f32_16x16x32_bf16(af1, wf0, acc[1][0], 0, 0, 0);
        acc[1][1] = __builtin_amdgcn_mfma_f32_16x16x32_bf16(af1, wf1, acc[1][1], 0, 0, 0);
        if (s + 1 < 3) __syncthreads();
    }

    #pragma unroll
    for (int mi = 0; mi < 2; ++mi) {
        #pragma unroll
        for (int ni = 0; ni < 2; ++ni) {
            int col = wn + ni * 16 + lr;
            if (col >= XDB) continue;
            #pragma unroll
            for (int r = 0; r < 4; ++r) {
                int row = bm + wm + mi * 16 + qq * 4 + r;
                if (row >= BB * LF) continue;
                atomicAdd(&xdo[(size_t)row * XDB + col], acc[mi][ni][r]);
            }
        }
    }
}

// cls row: residual[b, 128, :] = cls + pos[128]
__global__ void cls_k(const float* __restrict__ cls, const float* __restrict__ pos,
                      float* __restrict__ residual) {
    int b = blockIdx.x, t = threadIdx.x;
    residual[(size_t)(b * LF + POSROW) * DMODEL + t] =
        cls[t] + pos[(size_t)POSROW * DMODEL + t];
}

// row-wise layernorm STATS over 384 -> (mean, rstd) per row
__global__ __launch_bounds__(128) void lnstat_k(const float* __restrict__ X,
                                                float2* __restrict__ st) {
    int r = blockIdx.x;
    const float* x = X + (size_t)r * DMODEL;
    int t = threadIdx.x;
    float v0 = x[t], v1 = x[t + 128], v2 = x[t + 256];
    float s = v0 + v1 + v2;
    float sq = v0 * v0 + v1 * v1 + v2 * v2;
    #pragma unroll
    for (int o = 32; o > 0; o >>= 1) {
        s += __shfl_down(s, o);
        sq += __shfl_down(sq, o);
    }
    __shared__ float ls[2], lq[2];
    if ((t & 63) == 0) { ls[t >> 6] = s; lq[t >> 6] = sq; }
    __syncthreads();
    if (t == 0) {
        float S = ls[0] + ls[1], Q = lq[0] + lq[1];
        float mean = S * (1.f / 384.f);
        float var = Q * (1.f / 384.f) - mean * mean;
        st[r] = make_float2(mean, rsqrtf(var + 1e-5f));
    }
}

// ---------------------------------------------------------------------------
// Chunked associative scan with FUSED dt-projection+softplus.
// dt[row][d] = softplus(bias[d] + sum_k xdb[row][k] * dw[d][k]), k<24.
// ---------------------------------------------------------------------------
__global__ __launch_bounds__(256) void scanA_k(
    const float* __restrict__ xcf, const float* __restrict__ xcb,
    const float* __restrict__ xdbf, const float* __restrict__ xdbb,
    const float* __restrict__ alf, const float* __restrict__ alb,
    const float* __restrict__ dwf, const float* __restrict__ dbf,
    const float* __restrict__ dwb, const float* __restrict__ dbb,
    float* __restrict__ hpart, float* __restrict__ sumd) {
    const int t = threadIdx.x;
    const int y = blockIdx.y;            // b*2+br
    const int b = y >> 1, br = y & 1;
    const int c = blockIdx.z;
    const int d = blockIdx.x * 256 + t;
    const float* xc  = br ? xcb  : xcf;
    const float* xdb = br ? xdbb : xdbf;
    const float* Al  = br ? alb  : alf;
    const float* dw  = br ? dwb  : dwf;
    const float* dbi = br ? dbb  : dbf;

    float An[NST];
    #pragma unroll
    for (int n = 0; n < NST; ++n) An[n] = -__expf(Al[(size_t)d * NST + n]);
    float wdt[DTR];
    #pragma unroll
    for (int k = 0; k < DTR; k += 4)
        *(float4*)&wdt[k] = *(const float4*)&dw[(size_t)d * DTR + k];
    float dbv = dbi[d];

    __shared__ float sXD[CL][DTR];
    __shared__ float sB[CL][NST];
    for (int idx = t; idx < CL * DTR; idx += 256) {
        int s0 = idx / DTR, j0 = idx - s0 * DTR;
        int l0 = c * CL + s0;
        sXD[s0][j0] = (l0 < LF) ? xdb[(size_t)(b * LF + l0) * XDB + j0] : 0.f;
    }
    {
        int s0 = t >> 4, j0 = t & 15;
        int l0 = c * CL + s0;
        sB[s0][j0] = (l0 < LF) ? xdb[(size_t)(b * LF + l0) * XDB + DTR + j0] : 0.f;
    }
    __syncthreads();

    float h[NST] = {};
    float sdt = 0.f;
    #pragma unroll
    for (int s = 0; s < CL; ++s) {
        int l = c * CL + s;
        if (l < LF) {
            int row = b * LF + l;
            float dtv = dbv;
            #pragma unroll
            for (int k = 0; k < DTR; ++k) dtv += sXD[s][k] * wdt[k];
            dtv = softplusf(dtv);
            float xcv = xc[(size_t)row * DIN + d];
            sdt += dtv;
            float dtx = dtv * xcv;
            #pragma unroll
            for (int n = 0; n < NST; ++n)
                h[n] = __expf(dtv * An[n]) * h[n] + dtx * sB[s][n];
        }
    }
    size_t base = (size_t)(c * 8 + y) * NST;
    #pragma unroll
    for (int n = 0; n < NST; ++n) hpart[(base + n) * DIN + d] = h[n];
    sumd[(size_t)(c * 8 + y) * DIN + d] = sdt;
}

__global__ __launch_bounds__(256) void scanC_k(
    const float* __restrict__ xcf, const float* __restrict__ xcb,
    const float* __restrict__ xdbf, const float* __restrict__ xdbb,
    const float* __restrict__ xz,
    const float* __restrict__ alf, const float* __restrict__ dpf,
    const float* __restrict__ alb, const float* __restrict__ dpb,
    const float* __restrict__ dwf, const float* __restrict__ dbf,
    const float* __restrict__ dwb, const float* __restrict__ dbb,
    const float* __restrict__ hpart, const float* __restrict__ sumd,
    float* __restrict__ yf, float* __restrict__ yb) {
    const int t = threadIdx.x;
    const int y = blockIdx.y;
    const int b = y >> 1, br = y & 1;
    const int c = blockIdx.z;
    const int d = blockIdx.x * 256 + t;
    const float* xc  = br ? xcb  : xcf;
    const float* xdb = br ? xdbb : xdbf;
    const float* Al  = br ? alb  : alf;
    const float* Dpp = br ? dpb  : dpf;
    const float* dw  = br ? dwb  : dwf;
    const float* dbi = br ? dbb  : dbf;
    float* yo        = br ? yb   : yf;

    float An[NST];
    #pragma unroll
    for (int n = 0; n < NST; ++n) An[n] = -__expf(Al[(size_t)d * NST + n]);
    float wdt[DTR];
    #pragma unroll
    for (int k = 0; k < DTR; k += 4)
        *(float4*)&wdt[k] = *(const float4*)&dw[(size_t)d * DTR + k];
    float dbv = dbi[d];
    float Dv = Dpp[d];

    __shared__ float sXD[CL][DTR];
    __shared__ float sB[CL][NST];
    __shared__ float sC[CL][NST];
    for (int idx = t; idx < CL * DTR; idx += 256) {
        int s0 = idx / DTR, j0 = idx - s0 * DTR;
        int l0 = c * CL + s0;
        sXD[s0][j0] = (l0 < LF) ? xdb[(size_t)(b * LF + l0) * XDB + j0] : 0.f;
    }
    {
        int s0 = t >> 4, j0 = t & 15;
        int l0 = c * CL + s0;
        size_t rb = (size_t)(b * LF + l0) * XDB + DTR;
        sB[s0][j0] = (l0 < LF) ? xdb[rb + j0] : 0.f;
        sC[s0][j0] = (l0 < LF) ? xdb[rb + NST + j0] : 0.f;
    }
    __syncthreads();

    float h[NST] = {};
    for (int j = 0; j < c; ++j) {
        float sd = sumd[(size_t)(j * 8 + y) * DIN + d];
        size_t base = (size_t)(j * 8 + y) * NST;
        #pragma unroll
        for (int n = 0; n < NST; ++n)
            h[n] = __expf(An[n] * sd) * h[n] + hpart[(base + n) * DIN + d];
    }

    #pragma unroll
    for (int s = 0; s < CL; ++s) {
        int l = c * CL + s;
        if (l < LF) {
            int row = b * LF + l;
            float dtv = dbv;
            #pragma unroll
            for (int k = 0; k < DTR; ++k) dtv += sXD[s][k] * wdt[k];
            dtv = softplusf(dtv);
            float xcv = xc[(size_t)row * DIN + d];
            int zl = br ? (LF - 1 - l) : l;
            float zv = xz[(size_t)(b * LF + zl) * (2 * DIN) + DIN + d];
            float dtx = dtv * xcv;
            float acc = 0.f;
            #pragma unroll
            for (int n = 0; n < NST; ++n) {
                h[n] = __expf(dtv * An[n]) * h[n] + dtx * sB[s][n];
                acc += h[n] * sC[s][n];
            }
            yo[(size_t)row * DIN + d] = (acc + xcv * Dv) * siluf(zv);
        }
    }
}

// final LN(row POS) + command MLP + add -> f32 out
__global__ __launch_bounds__(384) void final_k(
    const float* __restrict__ residual,
    const float* __restrict__ lnw, const float* __restrict__ lnb,
    const float* __restrict__ sv, const float* __restrict__ act,
    const float* __restrict__ cw1, const float* __restrict__ cb1,
    const float* __restrict__ cw2, const float* __restrict__ cb2,
    float* __restrict__ out) {
    int b = blockIdx.x, t = threadIdx.x;
    const float* x = residual + (size_t)(b * LF + POSROW) * DMODEL;
    float v = x[t];
    float s = v, sq = v * v;
    #pragma unroll
    for (int o = 32; o > 0; o >>= 1) {
        s += __shfl_down(s, o);
        sq += __shfl_down(sq, o);
    }
    __shared__ float ls[6], lq[6], hid[DMODEL], cmdin[20];
    if ((t & 63) == 0) { ls[t >> 6] = s; lq[t >> 6] = sq; }
    if (t < 20) cmdin[t] = (t < 16) ? sv[b * 16 + t] : act[b * 4 + t - 16];
    __syncthreads();
    float S = 0.f, Q = 0.f;
    #pragma unroll
    for (int w = 0; w < 6; ++w) { S += ls[w]; Q += lq[w]; }
    float mean = S * (1.f / 384.f);
    float var = Q * (1.f / 384.f) - mean * mean;
    float rs = rsqrtf(var + 1e-5f);
    float vis = (v - mean) * rs * lnw[t] + lnb[t];
    float a1 = cb1[t];
    #pragma unroll
    for (int k = 0; k < 20; ++k) a1 += cmdin[k] * cw1[t * 20 + k];
    hid[t] = fmaxf(a1, 0.f);
    __syncthreads();
    float a2 = cb2[t];
    for (int k = 0; k < DMODEL; ++k) a2 += hid[k] * cw2[t * DMODEL + k];
    out[b * DMODEL + t] = vis + a2;
}

extern "C" void kernel_launch(void* const* d_in, const int* in_sizes, int n_in,
                              void* d_out, int out_size, void* d_ws, size_t ws_size,
                              hipStream_t stream) {
    const float* depth_seq = (const float*)d_in[0];
    const float* state_vec = (const float*)d_in[1];
    const float* action    = (const float*)d_in[2];
    const float* patch_w   = (const float*)d_in[3];
    const float* patch_b   = (const float*)d_in[4];
    const float* cls_token = (const float*)d_in[5];
    const float* pos_embed = (const float*)d_in[6];
    const float* ln_w      = (const float*)d_in[7];
    const float* ln_b      = (const float*)d_in[8];
    const float* in_proj_w = (const float*)d_in[9];
    const float* conv_w    = (const float*)d_in[10];
    const float* conv_b    = (const float*)d_in[11];
    const float* conv_wb   = (const float*)d_in[12];
    const float* conv_bb   = (const float*)d_in[13];
    const float* xproj_w   = (const float*)d_in[14];
    const float* xproj_wb  = (const float*)d_in[15];
    const float* dtproj_w  = (const float*)d_in[16];
    const float* dtproj_b  = (const float*)d_in[17];
    const float* dtproj_wb = (const float*)d_in[18];
    const float* dtproj_bb = (const float*)d_in[19];
    const float* A_log     = (const float*)d_in[20];
    const float* A_logb    = (const float*)d_in[21];
    const float* Dp        = (const float*)d_in[22];
    const float* Dpb       = (const float*)d_in[23];
    const float* out_w     = (const float*)d_in[24];
    const float* lnf_w     = (const float*)d_in[25];
    const float* lnf_b     = (const float*)d_in[26];
    const float* cw1       = (const float*)d_in[27];
    const float* cb1       = (const float*)d_in[28];
    const float* cw2       = (const float*)d_in[29];
    const float* cb2       = (const float*)d_in[30];

    const int M = BB * LF;  // 1028
    float* ws = (float*)d_ws;
    size_t o = 0;
    float* residual = ws + o; o += (size_t)M * DMODEL;
    float* xz       = ws + o; o += (size_t)M * 2 * DIN;
    float* xcf      = ws + o; o += (size_t)M * DIN;
    float* xcb      = ws + o; o += (size_t)M * DIN;
    float* xdbf     = ws + o; o += (size_t)M * XDB;
    float* xdbb     = ws + o; o += (size_t)M * XDB;
    float* yfb      = ws + o; o += (size_t)M * DIN;
    float* ybb      = ws + o; o += (size_t)M * DIN;
    float* hpart    = ws + o; o += (size_t)NC * 8 * NST * DIN;
    float* sumd     = ws + o; o += (size_t)NC * 8 * DIN;
    float2* stats   = (float2*)(ws + o); o += (size_t)M * 2;
    (void)ws_size; (void)in_sizes; (void)n_in; (void)out_size;

    // patchify -> residual (bias + pos, cls gap), MFMA
    mgemm_k<1, 3><<<dim3(16, 6), 256, 0, stream>>>(
        nullptr, 0, patch_w, patch_b, residual, 1024, DMODEL, 256, 1,
        depth_seq, nullptr, pos_embed);
    cls_k<<<BB, DMODEL, 0, stream>>>(cls_token, pos_embed, residual);

    for (int i = 0; i < 4; ++i) {
        lnstat_k<<<M, 128, 0, stream>>>(residual, stats);
        // in_proj with fused LN: (1028 x 384) @ (384 x 1536)^T
        mgemm_k<3, 0><<<dim3(17, 24), 256, 0, stream>>>(
            residual, DMODEL, in_proj_w + (size_t)i * 2 * DIN * DMODEL, nullptr,
            xz, M, 2 * DIN, DMODEL, 1,
            (const float*)stats, ln_w + (size_t)i * DMODEL, ln_b + (size_t)i * DMODEL);
        // zero both xdb buffers (adjacent) for atomic split-K partials
        hipMemsetAsync(xdbf, 0, (size_t)2 * M * XDB * 4, stream);
        // fused conv+SiLU + xproj (writes xcf/xcb + atomic xdb partials)
        xp_k<<<dim3(17, 8, 2), 256, 0, stream>>>(
            xz, conv_w + (size_t)i * DIN * 4, conv_b + (size_t)i * DIN,
            conv_wb + (size_t)i * DIN * 4, conv_bb + (size_t)i * DIN,
            xproj_w + (size_t)i * XDB * DIN, xproj_wb + (size_t)i * XDB * DIN,
            xcf, xcb, xdbf, xdbb);
        // chunked scan with fused dt-projection
        scanA_k<<<dim3(3, 8, NC), 256, 0, stream>>>(
            xcf, xcb, xdbf, xdbb,
            A_log + (size_t)i * DIN * NST, A_logb + (size_t)i * DIN * NST,
            dtproj_w + (size_t)i * DIN * DTR, dtproj_b + (size_t)i * DIN,
            dtproj_wb + (size_t)i * DIN * DTR, dtproj_bb + (size_t)i * DIN,
            hpart, sumd);
        scanC_k<<<dim3(3, 8, NC), 256, 0, stream>>>(
            xcf, xcb, xdbf, xdbb, xz,
            A_log + (size_t)i * DIN * NST, Dp + (size_t)i * DIN,
            A_logb + (size_t)i * DIN * NST, Dpb + (size_t)i * DIN,
            dtproj_w + (size_t)i * DIN * DTR, dtproj_b + (size_t)i * DIN,
            dtproj_wb + (size_t)i * DIN * DTR, dtproj_bb + (size_t)i * DIN,
            hpart, sumd, yfb, ybb);
        // out_proj flip-add, split-K 4, atomicAdd accumulate into residual
        mgemm_k<2, 4><<<dim3(17, 6 * 4), 256, 0, stream>>>(
            yfb, DIN, out_w + (size_t)i * DMODEL * DIN, nullptr,
            residual, M, DMODEL, DIN, 4, nullptr, ybb, nullptr);
    }

    final_k<<<BB, DMODEL, 0, stream>>>(
        residual, lnf_w, lnf_b, state_vec, action, cw1, cb1, cw2, cb2,
        (float*)d_out);
}